// Round 2
// baseline (943.851 us; speedup 1.0000x reference)
//
#include <hip/hip_runtime.h>

#define N_SAMPLES 131072
#define N_CLASSES 1000
#define BINS 10

// d_ws layout:
//   [0, N_SAMPLES) floats          : values[i] = logsumexp(pred_i) - pred_i[t_i]  (>= 0)
//   at N_SAMPLES (as uint*) slot 0 : vmax bits (atomicMax on uint; valid since values >= 0)

// ---------------------------------------------------------------------------
// Kernel 1: per-row CE value + fused grid max (one wave per row)
// ---------------------------------------------------------------------------
__global__ __launch_bounds__(256) void values_max_kernel(const float* __restrict__ pred,
                                                         const int* __restrict__ target,
                                                         float* __restrict__ values,
                                                         unsigned int* __restrict__ vmax_bits) {
    __shared__ float smax[4];
    const int wave = threadIdx.x >> 6;   // 4 waves/block, 1 row/wave
    const int lane = threadIdx.x & 63;
    const int row  = blockIdx.x * 4 + wave;

    const float4* __restrict__ rp = (const float4*)(pred + (size_t)row * N_CLASSES);

    float4 r[4];
    float lmax = -INFINITY;
#pragma unroll
    for (int k = 0; k < 4; ++k) {
        int idx = k * 64 + lane;          // 250 float4 = 1000 floats exactly
        if (idx < 250) {
            r[k] = rp[idx];
            lmax = fmaxf(lmax, fmaxf(fmaxf(r[k].x, r[k].y), fmaxf(r[k].z, r[k].w)));
        }
    }
#pragma unroll
    for (int off = 32; off > 0; off >>= 1)
        lmax = fmaxf(lmax, __shfl_xor(lmax, off, 64));

    float s = 0.f;
#pragma unroll
    for (int k = 0; k < 4; ++k) {
        int idx = k * 64 + lane;
        if (idx < 250) {
            s += __expf(r[k].x - lmax);
            s += __expf(r[k].y - lmax);
            s += __expf(r[k].z - lmax);
            s += __expf(r[k].w - lmax);
        }
    }
#pragma unroll
    for (int off = 32; off > 0; off >>= 1)
        s += __shfl_xor(s, off, 64);

    float v = 0.f;
    if (lane == 0) {
        float xt = pred[(size_t)row * N_CLASSES + target[row]];  // L1-hot: row just read
        v = logf(s) + lmax - xt;         // logsumexp - x_t, always >= 0
        values[row] = v;
        smax[wave] = v;
    }
    __syncthreads();
    if (threadIdx.x == 0) {
        float bm = fmaxf(fmaxf(smax[0], smax[1]), fmaxf(smax[2], smax[3]));
        atomicMax(vmax_bits, __float_as_uint(bm));  // one atomic per block
    }
}

// ---------------------------------------------------------------------------
// Kernel 2: single-block histogram + finalize.
// Uses cumulative form: cum[j] = #(vc >= j/10), cs[j] = sum(v | vc >= j/10);
// bin counts/sums are adjacent differences. Matches searchsorted(edges,'right')
// bit-exactly since edges[j] == (float)j/10.0f and edges[10] (=1+1e-6) never
// binds (vc <= 1.0).
// ---------------------------------------------------------------------------
__global__ __launch_bounds__(1024) void hist_final_kernel(const float* __restrict__ values,
                                                          const unsigned int* __restrict__ vmax_bits,
                                                          float* __restrict__ out) {
    __shared__ float scum[BINS];   // scum[j] ~ cum[j+1], j=0..8 used
    __shared__ float scs[BINS + 1];
    const int tid  = threadIdx.x;
    const int lane = tid & 63;
    const int wv   = tid >> 6;

    if (tid < BINS) scum[tid] = 0.f;
    if (tid < BINS + 1) scs[tid] = 0.f;
    __syncthreads();

    const float vmax = __uint_as_float(*vmax_bits);
    const float inv  = 1.0f / vmax;

    float edge[9];
#pragma unroll
    for (int j = 0; j < 9; ++j) edge[j] = (float)(j + 1) / 10.0f;  // edges 0.1..0.9

    float cum[9];   // cum[j-1] = count(vc >= edge j)
    float cs[10];   // cs[0] = total sum; cs[j] = sum(v | vc >= edge j)
#pragma unroll
    for (int j = 0; j < 9; ++j) cum[j] = 0.f;
#pragma unroll
    for (int j = 0; j < 10; ++j) cs[j] = 0.f;

    const float4* __restrict__ vp = (const float4*)values;
#pragma unroll 4
    for (int k = 0; k < N_SAMPLES / 4 / 1024; ++k) {
        float4 v4 = vp[tid + 1024 * k];
        float vv[4] = {v4.x, v4.y, v4.z, v4.w};
#pragma unroll
        for (int c = 0; c < 4; ++c) {
            float v  = vv[c];
            float vc = v * inv;
            cs[0] += v;
#pragma unroll
            for (int j = 0; j < 9; ++j) {
                bool m = (vc >= edge[j]);
                cum[j] += m ? 1.f : 0.f;
                cs[j + 1] += m ? v : 0.f;
            }
        }
    }

    // wave butterfly reduce the 19 accumulators
#pragma unroll
    for (int off = 32; off > 0; off >>= 1) {
#pragma unroll
        for (int j = 0; j < 9; ++j) cum[j] += __shfl_xor(cum[j], off, 64);
#pragma unroll
        for (int j = 0; j < 10; ++j) cs[j] += __shfl_xor(cs[j], off, 64);
    }
    if (lane == 0) {
        (void)wv;
#pragma unroll
        for (int j = 0; j < 9; ++j) atomicAdd(&scum[j], cum[j]);
#pragma unroll
        for (int j = 0; j < 10; ++j) atomicAdd(&scs[j], cs[j]);
    }
    __syncthreads();

    if (tid == 0) {
        float c_edge[11], s_edge[11];
        c_edge[0] = (float)N_SAMPLES;
        s_edge[0] = scs[0];
#pragma unroll
        for (int j = 1; j <= 9; ++j) { c_edge[j] = scum[j - 1]; s_edge[j] = scs[j]; }
        c_edge[10] = 0.f; s_edge[10] = 0.f;

        int nn = 0;
        float acc = 0.f;
#pragma unroll
        for (int b = 0; b < BINS; ++b) {
            float cb = c_edge[b] - c_edge[b + 1];
            float sb = s_edge[b] - s_edge[b + 1];
            if (cb > 0.5f) { ++nn; acc += sb / cb; }
        }
        float nne = (nn > 0) ? (float)nn : 1.f;
        out[0] = acc / nne;   // == sum_i weights[i] * values[i]
    }
}

extern "C" void kernel_launch(void* const* d_in, const int* in_sizes, int n_in,
                              void* d_out, int out_size, void* d_ws, size_t ws_size,
                              hipStream_t stream) {
    const float* pred  = (const float*)d_in[0];
    const int* target  = (const int*)d_in[1];
    float* out         = (float*)d_out;

    float* values           = (float*)d_ws;
    unsigned int* vmax_bits = (unsigned int*)((char*)d_ws + (size_t)N_SAMPLES * sizeof(float));

    hipMemsetAsync(vmax_bits, 0, sizeof(unsigned int), stream);  // values >= 0, so 0-bits = -max
    values_max_kernel<<<N_SAMPLES / 4, 256, 0, stream>>>(pred, target, values, vmax_bits);
    hist_final_kernel<<<1, 1024, 0, stream>>>(values, vmax_bits, out);
}